// Round 1
// baseline (717.033 us; speedup 1.0000x reference)
//
#include <hip/hip_runtime.h>

typedef unsigned short u16;
typedef __attribute__((ext_vector_type(4))) float f32x4;
typedef __attribute__((ext_vector_type(8))) __bf16 bf16x8;
typedef __attribute__((ext_vector_type(8))) unsigned short u16x8;
typedef __attribute__((ext_vector_type(4))) unsigned short u16x4;

__device__ __forceinline__ u16 f2bf(float f) {
  union { float f; unsigned u; } v; v.f = f;
  unsigned r = v.u + 0x7FFFu + ((v.u >> 16) & 1u);
  return (u16)(r >> 16);
}

__device__ __forceinline__ void async16(const void* g, void* l) {
  __builtin_amdgcn_global_load_lds(
      (const __attribute__((address_space(1))) unsigned int*)g,
      (__attribute__((address_space(3))) unsigned int*)l, 16, 0, 0);
}

// ---------------- elementwise f32 -> bf16 ----------------
__global__ __launch_bounds__(256) void cvt_f32_bf16(const float* __restrict__ in,
                                                    u16* __restrict__ out, int n4) {
  int i = blockIdx.x * 256 + threadIdx.x;
  if (i >= n4) return;
  f32x4 v = *(const f32x4*)(in + (long)i * 4);
  u16x4 o;
#pragma unroll
  for (int j = 0; j < 4; j++) o[j] = f2bf(v[j]);
  *(u16x4*)(out + (long)i * 4) = o;
}

// ---------------- transpose + convert: W[K][N] f32 -> Wt[N][K] bf16 ----------------
__global__ __launch_bounds__(256) void transpose_cvt(const float* __restrict__ W,
                                                     u16* __restrict__ Wt, int K, int N) {
  __shared__ float tile[32][33];
  int n0 = blockIdx.x * 32, k0 = blockIdx.y * 32;
  int tx = threadIdx.x & 31, ty = threadIdx.x >> 5;
#pragma unroll
  for (int i = 0; i < 32; i += 8)
    tile[ty + i][tx] = W[(long)(k0 + ty + i) * N + n0 + tx];
  __syncthreads();
#pragma unroll
  for (int i = 0; i < 32; i += 8)
    Wt[(long)(n0 + ty + i) * K + k0 + tx] = f2bf(tile[tx][ty + i]);
}

// ---------------- GEMM: C[M,N] = A[M,K](bf16) @ Bt[N,K](bf16)^T ----------------
template <int BIAS, int GELU, int OBF>
__global__ __launch_bounds__(256, 2) void gemm128(const u16* __restrict__ A,
                                                  const u16* __restrict__ Bt,
                                                  void* __restrict__ Cp,
                                                  const float* __restrict__ bias,
                                                  int M, int N, int K) {
  __shared__ u16 As[128 * 32];
  __shared__ u16 Bs[128 * 32];
  const int t = threadIdx.x, ln = t & 63, wv = t >> 6;
  const int wr = wv >> 1, wc = wv & 1;
  const int lr = ln & 15, lg = ln >> 4;
  const int m0 = blockIdx.y * 128, n0 = blockIdx.x * 128;

  const u16* gA = A + (long)(m0 + (t >> 2)) * K + (t & 3) * 8;
  const u16* gA2 = gA + (long)64 * K;
  const u16* gB = Bt + (long)(n0 + (t >> 2)) * K + (t & 3) * 8;
  const u16* gB2 = gB + (long)64 * K;
  char* ldsA = (char*)As + wv * 1024;
  char* ldsB = (char*)Bs + wv * 1024;

  f32x4 acc[4][4] = {};

  for (int kt = 0; kt < K; kt += 32) {
    __syncthreads();
    async16(gA, ldsA);
    async16(gA2, ldsA + 4096);
    async16(gB, ldsB);
    async16(gB2, ldsB + 4096);
    gA += 32; gA2 += 32; gB += 32; gB2 += 32;
    __syncthreads();
    bf16x8 aF[4], bF[4];
#pragma unroll
    for (int i = 0; i < 4; i++) {
      aF[i] = *(const bf16x8*)&As[(wr * 64 + i * 16 + lr) * 32 + lg * 8];
      bF[i] = *(const bf16x8*)&Bs[(wc * 64 + i * 16 + lr) * 32 + lg * 8];
    }
#pragma unroll
    for (int i = 0; i < 4; i++)
#pragma unroll
      for (int j = 0; j < 4; j++)
        acc[i][j] = __builtin_amdgcn_mfma_f32_16x16x32_bf16(aF[i], bF[j], acc[i][j], 0, 0, 0);
  }

#pragma unroll
  for (int i = 0; i < 4; i++) {
    int rbase = m0 + wr * 64 + i * 16 + lg * 4;
#pragma unroll
    for (int j = 0; j < 4; j++) {
      int col = n0 + wc * 64 + j * 16 + lr;
      float bv = BIAS ? bias[col] : 0.f;
#pragma unroll
      for (int r = 0; r < 4; r++) {
        float v = acc[i][j][r] + bv;
        if (GELU) v = v / (1.f + __expf(-1.702f * v));
        if (OBF) ((u16*)Cp)[(long)(rbase + r) * N + col] = f2bf(v);
        else ((float*)Cp)[(long)(rbase + r) * N + col] = v;
      }
    }
  }
}

// ---------------- flash attention ----------------
// qkv: [8192][3072] bf16 (Q|K|V each 1024 cols, head h at h*64). out: [8192][1024] bf16.
__global__ __launch_bounds__(256, 2) void attn_kernel(const u16* __restrict__ qkv,
                                                      u16* __restrict__ out) {
  const int b = blockIdx.y >> 4, h = blockIdx.y & 15;
  const int q0 = blockIdx.x * 64;
  const int t = threadIdx.x, wv = t >> 6, ln = t & 63;
  const int lr = ln & 15, lg = ln >> 4;
  __shared__ u16 Ks[64 * 64];
  __shared__ u16 Vt[64 * 64];
  __shared__ u16 Pl[4][16 * 64];

  const long tok0 = (long)b * 2048;
  bf16x8 aQ[2];
  {
    long row = tok0 + q0 + wv * 16 + lr;
#pragma unroll
    for (int kf = 0; kf < 2; kf++)
      aQ[kf] = *(const bf16x8*)&qkv[row * 3072 + h * 64 + kf * 32 + lg * 8];
  }
  float m_i[4], l_i[4];
  f32x4 accO[4] = {};
#pragma unroll
  for (int j = 0; j < 4; j++) { m_i[j] = -1e30f; l_i[j] = 0.f; }

  const int r = t >> 3, c8 = (t & 7) * 8;
  char* ldsK = (char*)Ks + wv * 1024;

  for (int kt = 0; kt < 2048; kt += 64) {
    __syncthreads();
    {
      const u16* gK = qkv + (tok0 + kt + r) * 3072 + 1024 + h * 64 + c8;
      async16(gK, ldsK);
      async16(gK + (long)32 * 3072, ldsK + 4096);
      u16x8 v0 = *(const u16x8*)&qkv[(tok0 + kt + r) * 3072 + 2048 + h * 64 + c8];
      u16x8 v1 = *(const u16x8*)&qkv[(tok0 + kt + r + 32) * 3072 + 2048 + h * 64 + c8];
#pragma unroll
      for (int j = 0; j < 8; j++) {
        Vt[(c8 + j) * 64 + r] = v0[j];
        Vt[(c8 + j) * 64 + r + 32] = v1[j];
      }
    }
    __syncthreads();

    f32x4 accS[4];
#pragma unroll
    for (int nc = 0; nc < 4; nc++) {
      f32x4 s = {};
#pragma unroll
      for (int kf = 0; kf < 2; kf++) {
        bf16x8 bK = *(const bf16x8*)&Ks[(nc * 16 + lr) * 64 + kf * 32 + lg * 8];
        s = __builtin_amdgcn_mfma_f32_16x16x32_bf16(aQ[kf], bK, s, 0, 0, 0);
      }
      accS[nc] = s * 0.125f;
    }

    float corr[4];
#pragma unroll
    for (int j = 0; j < 4; j++) {
      float v = fmaxf(fmaxf(accS[0][j], accS[1][j]), fmaxf(accS[2][j], accS[3][j]));
#pragma unroll
      for (int sft = 1; sft < 16; sft <<= 1) v = fmaxf(v, __shfl_xor(v, sft));
      float mn = fmaxf(m_i[j], v);
      corr[j] = __expf(m_i[j] - mn);
      m_i[j] = mn;
    }
    float rs[4] = {0.f, 0.f, 0.f, 0.f};
#pragma unroll
    for (int nc = 0; nc < 4; nc++) {
#pragma unroll
      for (int j = 0; j < 4; j++) {
        float p = __expf(accS[nc][j] - m_i[j]);
        rs[j] += p;
        Pl[wv][(lg * 4 + j) * 64 + nc * 16 + lr] = f2bf(p);
      }
    }
#pragma unroll
    for (int j = 0; j < 4; j++) {
      float rr = rs[j];
#pragma unroll
      for (int sft = 1; sft < 16; sft <<= 1) rr += __shfl_xor(rr, sft);
      l_i[j] = l_i[j] * corr[j] + rr;
#pragma unroll
      for (int d = 0; d < 4; d++) accO[d][j] *= corr[j];
    }
#pragma unroll
    for (int kf = 0; kf < 2; kf++) {
      bf16x8 aP = *(const bf16x8*)&Pl[wv][lr * 64 + kf * 32 + lg * 8];
#pragma unroll
      for (int d = 0; d < 4; d++) {
        bf16x8 bV = *(const bf16x8*)&Vt[(d * 16 + lr) * 64 + kf * 32 + lg * 8];
        accO[d] = __builtin_amdgcn_mfma_f32_16x16x32_bf16(aP, bV, accO[d], 0, 0, 0);
      }
    }
  }
#pragma unroll
  for (int d = 0; d < 4; d++) {
#pragma unroll
    for (int j = 0; j < 4; j++) {
      float v = accO[d][j] / l_i[j];
      out[(tok0 + q0 + wv * 16 + lg * 4 + j) * 1024 + h * 64 + d * 16 + lr] = f2bf(v);
    }
  }
}

// ---------------- fused add + layernorm (1024 cols, 1 row per block) ----------------
template <int WB>
__global__ __launch_bounds__(256) void ln_kernel(const float* __restrict__ xin,
                                                 const float* __restrict__ res,
                                                 const float* __restrict__ g,
                                                 const float* __restrict__ be,
                                                 float* __restrict__ of,
                                                 u16* __restrict__ ob) {
  int row = blockIdx.x, t = threadIdx.x;
  long base = (long)row * 1024 + t * 4;
  f32x4 a = *(const f32x4*)(xin + base);
  f32x4 bv = *(const f32x4*)(res + base);
  f32x4 v = a + bv;
  float s = v[0] + v[1] + v[2] + v[3];
  float ss = v[0] * v[0] + v[1] * v[1] + v[2] * v[2] + v[3] * v[3];
#pragma unroll
  for (int o = 1; o < 64; o <<= 1) { s += __shfl_xor(s, o); ss += __shfl_xor(ss, o); }
  __shared__ float sm[8];
  if ((t & 63) == 0) { sm[t >> 6] = s; sm[4 + (t >> 6)] = ss; }
  __syncthreads();
  s = sm[0] + sm[1] + sm[2] + sm[3];
  ss = sm[4] + sm[5] + sm[6] + sm[7];
  float mu = s * 0.0009765625f;
  float var = ss * 0.0009765625f - mu * mu;
  float inv = rsqrtf(var + 1e-5f);
  f32x4 gg = *(const f32x4*)(g + t * 4);
  f32x4 bb = *(const f32x4*)(be + t * 4);
  f32x4 y;
#pragma unroll
  for (int j = 0; j < 4; j++) y[j] = (v[j] - mu) * inv * gg[j] + bb[j];
  *(f32x4*)(of + base) = y;
  if (WB) {
    u16x4 o4;
#pragma unroll
    for (int j = 0; j < 4; j++) o4[j] = f2bf(y[j]);
    *(u16x4*)(ob + base) = o4;
  }
}

// ---------------- launch ----------------
extern "C" void kernel_launch(void* const* d_in, const int* in_sizes, int n_in,
                              void* d_out, int out_size, void* d_ws, size_t ws_size,
                              hipStream_t stream) {
  const float* x = (const float*)d_in[0];
  const float* Wqkv = (const float*)d_in[1];
  const float* Wo = (const float*)d_in[2];
  const float* bo = (const float*)d_in[3];
  const float* g1 = (const float*)d_in[4];
  const float* be1 = (const float*)d_in[5];
  const float* W1 = (const float*)d_in[6];
  const float* b1 = (const float*)d_in[7];
  const float* W2 = (const float*)d_in[8];
  const float* b2 = (const float*)d_in[9];
  const float* g2 = (const float*)d_in[10];
  const float* be2 = (const float*)d_in[11];
  float* out = (float*)d_out;
  char* ws = (char*)d_ws;

  // workspace layout (bytes); regions overlaid by lifetime
  u16* xb = (u16*)(ws + 0);                  // 16.78M  [dead after GEMM1]
  u16* qkvb = (u16*)(ws + 16777216);         // 50.33M  [dead after attn]
  u16* h1b = (u16*)(ws + 0);                 // 67.11M  reuses xb+qkvb
  u16* attnb = (u16*)(ws + 67108864);        // 16.78M  [dead after GEMM2]
  float* proj = (float*)(ws + 83886080);     // 33.55M  [dead after LN1]
  float* ff = (float*)(ws + 67108864);       // 33.55M  reuses attnb(+proj head)
  float* x1f = (float*)(ws + 117440512);     // 33.55M
  u16* x1b = (u16*)(ws + 150994944);         // 16.78M
  u16* wqkvt = (u16*)(ws + 167772160);       // 6.29M
  u16* wot = (u16*)(ws + 174063616);         // 2.10M
  u16* w1t = (u16*)(ws + 176160768);         // 8.39M
  u16* w2t = (u16*)(ws + 184549376);         // 8.39M  (end ~193M)

  // 1. converts / transposes
  cvt_f32_bf16<<<8192, 256, 0, stream>>>(x, xb, 2097152);
  transpose_cvt<<<dim3(96, 32), 256, 0, stream>>>(Wqkv, wqkvt, 1024, 3072);
  transpose_cvt<<<dim3(32, 32), 256, 0, stream>>>(Wo, wot, 1024, 1024);
  transpose_cvt<<<dim3(128, 32), 256, 0, stream>>>(W1, w1t, 1024, 4096);
  transpose_cvt<<<dim3(32, 128), 256, 0, stream>>>(W2, w2t, 4096, 1024);
  // 2. qkv = x @ Wqkv
  gemm128<0, 0, 1><<<dim3(24, 64), 256, 0, stream>>>(xb, wqkvt, qkvb, nullptr, 8192, 3072, 1024);
  // 3. attention
  attn_kernel<<<dim3(32, 64), 256, 0, stream>>>(qkvb, attnb);
  // 4. proj = attn @ Wo + bo
  gemm128<1, 0, 0><<<dim3(8, 64), 256, 0, stream>>>(attnb, wot, proj, bo, 8192, 1024, 1024);
  // 5. x1 = LN(x + proj)
  ln_kernel<1><<<8192, 256, 0, stream>>>(x, proj, g1, be1, x1f, x1b);
  // 6. h1 = gelu(x1 @ W1 + b1)
  gemm128<1, 1, 1><<<dim3(32, 64), 256, 0, stream>>>(x1b, w1t, h1b, b1, 8192, 4096, 1024);
  // 7. ff = h1 @ W2 + b2
  gemm128<1, 0, 0><<<dim3(8, 64), 256, 0, stream>>>(h1b, w2t, ff, b2, 8192, 1024, 4096);
  // 8. out = LN(x1 + ff)
  ln_kernel<0><<<8192, 256, 0, stream>>>(x1f, ff, g2, be2, out, nullptr);
}

// Round 2
// 560.143 us; speedup vs baseline: 1.2801x; 1.2801x over previous
//
#include <hip/hip_runtime.h>

typedef unsigned short u16;
typedef __attribute__((ext_vector_type(4))) float f32x4;
typedef __attribute__((ext_vector_type(8))) __bf16 bf16x8;
typedef __attribute__((ext_vector_type(8))) unsigned short u16x8;
typedef __attribute__((ext_vector_type(4))) unsigned short u16x4;

__device__ __forceinline__ u16 f2bf(float f) {
  union { float f; unsigned u; } v; v.f = f;
  unsigned r = v.u + 0x7FFFu + ((v.u >> 16) & 1u);
  return (u16)(r >> 16);
}

__device__ __forceinline__ void async16(const void* g, void* l) {
  __builtin_amdgcn_global_load_lds(
      (const __attribute__((address_space(1))) unsigned int*)g,
      (__attribute__((address_space(3))) unsigned int*)l, 16, 0, 0);
}

// ---------------- elementwise f32 -> bf16 ----------------
__global__ __launch_bounds__(256) void cvt_f32_bf16(const float* __restrict__ in,
                                                    u16* __restrict__ out, int n4) {
  int i = blockIdx.x * 256 + threadIdx.x;
  if (i >= n4) return;
  f32x4 v = *(const f32x4*)(in + (long)i * 4);
  u16x4 o;
#pragma unroll
  for (int j = 0; j < 4; j++) o[j] = f2bf(v[j]);
  *(u16x4*)(out + (long)i * 4) = o;
}

// ---------------- transpose + convert: W[K][N] f32 -> Wt[N][K] bf16 ----------------
__global__ __launch_bounds__(256) void transpose_cvt(const float* __restrict__ W,
                                                     u16* __restrict__ Wt, int K, int N) {
  __shared__ float tile[32][33];
  int n0 = blockIdx.x * 32, k0 = blockIdx.y * 32;
  int tx = threadIdx.x & 31, ty = threadIdx.x >> 5;
#pragma unroll
  for (int i = 0; i < 32; i += 8)
    tile[ty + i][tx] = W[(long)(k0 + ty + i) * N + n0 + tx];
  __syncthreads();
#pragma unroll
  for (int i = 0; i < 32; i += 8)
    Wt[(long)(n0 + ty + i) * K + k0 + tx] = f2bf(tile[tx][ty + i]);
}

// ---------------- V pre-transpose: qkv V block -> vt[bh][64 d][2048 keys] ----------------
__global__ __launch_bounds__(256) void vtrans(const u16* __restrict__ qkv,
                                              u16* __restrict__ vt) {
  const int bh = blockIdx.y, kt = blockIdx.x * 64;
  const int b = bh >> 4, h = bh & 15;
  const long tok0 = (long)b * 2048;
  const int t = threadIdx.x;
  const int r = t >> 3, c8 = (t & 7) * 8;
  u16x8 v0 = *(const u16x8*)&qkv[(tok0 + kt + r) * 3072 + 2048 + h * 64 + c8];
  u16x8 v1 = *(const u16x8*)&qkv[(tok0 + kt + r + 32) * 3072 + 2048 + h * 64 + c8];
#pragma unroll
  for (int j = 0; j < 8; j++) {
    vt[((long)bh * 64 + c8 + j) * 2048 + kt + r] = v0[j];
    vt[((long)bh * 64 + c8 + j) * 2048 + kt + r + 32] = v1[j];
  }
}

// ---------------- GEMM: C[M,N] = A[M,K](bf16) @ Bt[N,K](bf16)^T ----------------
template <int BIAS, int GELU, int OBF>
__global__ __launch_bounds__(256, 2) void gemm128(const u16* __restrict__ A,
                                                  const u16* __restrict__ Bt,
                                                  void* __restrict__ Cp,
                                                  const float* __restrict__ bias,
                                                  int M, int N, int K) {
  __shared__ u16 As[128 * 32];
  __shared__ u16 Bs[128 * 32];
  const int t = threadIdx.x, ln = t & 63, wv = t >> 6;
  const int wr = wv >> 1, wc = wv & 1;
  const int lr = ln & 15, lg = ln >> 4;
  const int m0 = blockIdx.y * 128, n0 = blockIdx.x * 128;

  const u16* gA = A + (long)(m0 + (t >> 2)) * K + (t & 3) * 8;
  const u16* gA2 = gA + (long)64 * K;
  const u16* gB = Bt + (long)(n0 + (t >> 2)) * K + (t & 3) * 8;
  const u16* gB2 = gB + (long)64 * K;
  char* ldsA = (char*)As + wv * 1024;
  char* ldsB = (char*)Bs + wv * 1024;

  f32x4 acc[4][4] = {};

  for (int kt = 0; kt < K; kt += 32) {
    __syncthreads();
    async16(gA, ldsA);
    async16(gA2, ldsA + 4096);
    async16(gB, ldsB);
    async16(gB2, ldsB + 4096);
    gA += 32; gA2 += 32; gB += 32; gB2 += 32;
    __syncthreads();
    bf16x8 aF[4], bF[4];
#pragma unroll
    for (int i = 0; i < 4; i++) {
      aF[i] = *(const bf16x8*)&As[(wr * 64 + i * 16 + lr) * 32 + lg * 8];
      bF[i] = *(const bf16x8*)&Bs[(wc * 64 + i * 16 + lr) * 32 + lg * 8];
    }
#pragma unroll
    for (int i = 0; i < 4; i++)
#pragma unroll
      for (int j = 0; j < 4; j++)
        acc[i][j] = __builtin_amdgcn_mfma_f32_16x16x32_bf16(aF[i], bF[j], acc[i][j], 0, 0, 0);
  }

#pragma unroll
  for (int i = 0; i < 4; i++) {
    int rbase = m0 + wr * 64 + i * 16 + lg * 4;
#pragma unroll
    for (int j = 0; j < 4; j++) {
      int col = n0 + wc * 64 + j * 16 + lr;
      float bv = BIAS ? bias[col] : 0.f;
#pragma unroll
      for (int r = 0; r < 4; r++) {
        float v = acc[i][j][r] + bv;
        if (GELU) v = v / (1.f + __expf(-1.702f * v));
        if (OBF) ((u16*)Cp)[(long)(rbase + r) * N + col] = f2bf(v);
        else ((float*)Cp)[(long)(rbase + r) * N + col] = v;
      }
    }
  }
}

// ---------------- flash attention (swizzled LDS, double-buffered DMA staging) -----
// qkv: [8192][3072] bf16. vt: [64 bh][64 d][2048 keys] bf16. out: [8192][1024] bf16.
__global__ __launch_bounds__(256, 4) void attn_kernel(const u16* __restrict__ qkv,
                                                      const u16* __restrict__ vt,
                                                      u16* __restrict__ out) {
  const int b = blockIdx.y >> 4, h = blockIdx.y & 15;
  const int q0 = blockIdx.x * 64;
  const int t = threadIdx.x, wv = t >> 6, ln = t & 63;
  const int lr = ln & 15, lg = ln >> 4;
  __shared__ u16 Ks[2][64 * 64];
  __shared__ u16 Vs[2][64 * 64];
  __shared__ u16 Pl[4][16 * 64];
  const long tok0 = (long)b * 2048;

  // Q fragments (held in regs for the whole kernel)
  bf16x8 aQ[2];
  {
    long row = tok0 + q0 + wv * 16 + lr;
#pragma unroll
    for (int kf = 0; kf < 2; kf++)
      aQ[kf] = *(const bf16x8*)&qkv[row * 3072 + h * 64 + kf * 32 + lg * 8];
  }

  // staging addresses (pre-swizzled global source -> linear LDS dest)
  const int sr = t >> 3;                       // row 0..31 (and +32)
  const int sc = ((t & 7) ^ (sr & 7)) * 8;     // swizzled u16 chunk
  const u16* gK = qkv + (tok0 + sr) * 3072 + 1024 + h * 64 + sc;
  const u16* gV = vt + ((long)(b * 16 + h) * 64 + sr) * 2048 + sc;
  char* dK = (char*)&Ks[0][0] + wv * 1024;
  char* dV = (char*)&Vs[0][0] + wv * 1024;

  float m_i[4], l_i[4];
  f32x4 accO[4] = {};
#pragma unroll
  for (int j = 0; j < 4; j++) { m_i[j] = -1e30f; l_i[j] = 0.f; }

  // prologue: stage tile 0 into buffer 0
  async16(gK, dK);
  async16(gK + (long)32 * 3072, dK + 4096);
  async16(gV, dV);
  async16(gV + (long)32 * 2048, dV + 4096);
  gK += (long)64 * 3072; gV += 64;

  for (int it = 0; it < 32; ++it) {
    const int cur = it & 1;
    if (it < 31) {
      char* nK = dK + (cur ^ 1) * 8192;
      char* nV = dV + (cur ^ 1) * 8192;
      async16(gK, nK);
      async16(gK + (long)32 * 3072, nK + 4096);
      async16(gV, nV);
      async16(gV + (long)32 * 2048, nV + 4096);
      gK += (long)64 * 3072; gV += 64;
      asm volatile("s_waitcnt vmcnt(4)" ::: "memory");
    } else {
      asm volatile("s_waitcnt vmcnt(0)" ::: "memory");
    }
    __builtin_amdgcn_s_barrier();
    __builtin_amdgcn_sched_barrier(0);
    const u16* Kc = &Ks[cur][0];
    const u16* Vc = &Vs[cur][0];

    // ---- S = Q K^T (swizzled reads) ----
    f32x4 accS[4];
#pragma unroll
    for (int nc = 0; nc < 4; nc++) {
      f32x4 s = {};
#pragma unroll
      for (int kf = 0; kf < 2; kf++) {
        int krow = nc * 16 + lr;
        bf16x8 bK = *(const bf16x8*)&Kc[krow * 64 + ((kf * 32 + lg * 8) ^ ((krow & 7) << 3))];
        s = __builtin_amdgcn_mfma_f32_16x16x32_bf16(aQ[kf], bK, s, 0, 0, 0);
      }
      accS[nc] = s * 0.125f;
    }

    // ---- online softmax ----
    float corr[4];
#pragma unroll
    for (int j = 0; j < 4; j++) {
      float v = fmaxf(fmaxf(accS[0][j], accS[1][j]), fmaxf(accS[2][j], accS[3][j]));
#pragma unroll
      for (int sft = 1; sft < 16; sft <<= 1) v = fmaxf(v, __shfl_xor(v, sft));
      float mn = fmaxf(m_i[j], v);
      corr[j] = __expf(m_i[j] - mn);
      m_i[j] = mn;
    }
    float rs[4] = {0.f, 0.f, 0.f, 0.f};
#pragma unroll
    for (int nc = 0; nc < 4; nc++) {
#pragma unroll
      for (int j = 0; j < 4; j++) {
        float p = __expf(accS[nc][j] - m_i[j]);
        rs[j] += p;
        int prow = lg * 4 + j;
        Pl[wv][prow * 64 + ((nc * 16 + lr) ^ ((prow & 7) << 3))] = f2bf(p);
      }
    }
#pragma unroll
    for (int j = 0; j < 4; j++) {
      float rr = rs[j];
#pragma unroll
      for (int sft = 1; sft < 16; sft <<= 1) rr += __shfl_xor(rr, sft);
      l_i[j] = l_i[j] * corr[j] + rr;
#pragma unroll
      for (int d = 0; d < 4; d++) accO[d][j] *= corr[j];
    }

    // ---- O += P V (swizzled reads) ----
#pragma unroll
    for (int kf = 0; kf < 2; kf++) {
      bf16x8 aP = *(const bf16x8*)&Pl[wv][lr * 64 + ((kf * 32 + lg * 8) ^ ((lr & 7) << 3))];
#pragma unroll
      for (int d = 0; d < 4; d++) {
        int vrow = d * 16 + lr;
        bf16x8 bV = *(const bf16x8*)&Vc[vrow * 64 + ((kf * 32 + lg * 8) ^ ((vrow & 7) << 3))];
        accO[d] = __builtin_amdgcn_mfma_f32_16x16x32_bf16(aP, bV, accO[d], 0, 0, 0);
      }
    }
    __builtin_amdgcn_s_barrier();
    __builtin_amdgcn_sched_barrier(0);
  }

#pragma unroll
  for (int d = 0; d < 4; d++) {
#pragma unroll
    for (int j = 0; j < 4; j++) {
      float v = accO[d][j] / l_i[j];
      out[(tok0 + q0 + wv * 16 + lg * 4 + j) * 1024 + h * 64 + d * 16 + lr] = f2bf(v);
    }
  }
}

// ---------------- fused add + layernorm (1024 cols, 1 row per block) ----------------
template <int WB>
__global__ __launch_bounds__(256) void ln_kernel(const float* __restrict__ xin,
                                                 const float* __restrict__ res,
                                                 const float* __restrict__ g,
                                                 const float* __restrict__ be,
                                                 float* __restrict__ of,
                                                 u16* __restrict__ ob) {
  int row = blockIdx.x, t = threadIdx.x;
  long base = (long)row * 1024 + t * 4;
  f32x4 a = *(const f32x4*)(xin + base);
  f32x4 bv = *(const f32x4*)(res + base);
  f32x4 v = a + bv;
  float s = v[0] + v[1] + v[2] + v[3];
  float ss = v[0] * v[0] + v[1] * v[1] + v[2] * v[2] + v[3] * v[3];
#pragma unroll
  for (int o = 1; o < 64; o <<= 1) { s += __shfl_xor(s, o); ss += __shfl_xor(ss, o); }
  __shared__ float sm[8];
  if ((t & 63) == 0) { sm[t >> 6] = s; sm[4 + (t >> 6)] = ss; }
  __syncthreads();
  s = sm[0] + sm[1] + sm[2] + sm[3];
  ss = sm[4] + sm[5] + sm[6] + sm[7];
  float mu = s * 0.0009765625f;
  float var = ss * 0.0009765625f - mu * mu;
  float inv = rsqrtf(var + 1e-5f);
  f32x4 gg = *(const f32x4*)(g + t * 4);
  f32x4 bb = *(const f32x4*)(be + t * 4);
  f32x4 y;
#pragma unroll
  for (int j = 0; j < 4; j++) y[j] = (v[j] - mu) * inv * gg[j] + bb[j];
  *(f32x4*)(of + base) = y;
  if (WB) {
    u16x4 o4;
#pragma unroll
    for (int j = 0; j < 4; j++) o4[j] = f2bf(y[j]);
    *(u16x4*)(ob + base) = o4;
  }
}

// ---------------- launch ----------------
extern "C" void kernel_launch(void* const* d_in, const int* in_sizes, int n_in,
                              void* d_out, int out_size, void* d_ws, size_t ws_size,
                              hipStream_t stream) {
  const float* x = (const float*)d_in[0];
  const float* Wqkv = (const float*)d_in[1];
  const float* Wo = (const float*)d_in[2];
  const float* bo = (const float*)d_in[3];
  const float* g1 = (const float*)d_in[4];
  const float* be1 = (const float*)d_in[5];
  const float* W1 = (const float*)d_in[6];
  const float* b1 = (const float*)d_in[7];
  const float* W2 = (const float*)d_in[8];
  const float* b2 = (const float*)d_in[9];
  const float* g2 = (const float*)d_in[10];
  const float* be2 = (const float*)d_in[11];
  float* out = (float*)d_out;
  char* ws = (char*)d_ws;

  // workspace layout (bytes); regions overlaid by lifetime
  u16* xb = (u16*)(ws + 0);                  // 16.78M  [dead after GEMM1]
  u16* qkvb = (u16*)(ws + 16777216);         // 50.33M  [dead after attn]
  u16* h1b = (u16*)(ws + 0);                 // 67.11M  reuses xb+qkvb
  u16* attnb = (u16*)(ws + 67108864);        // 16.78M  [dead after GEMM2]
  u16* vtb = (u16*)(ws + 83886080);          // 16.78M  [dead after attn]
  float* proj = (float*)(ws + 83886080);     // 33.55M  reuses vtb (written after attn)
  float* ff = (float*)(ws + 67108864);       // 33.55M  reuses attnb(+proj head)
  float* x1f = (float*)(ws + 117440512);     // 33.55M
  u16* x1b = (u16*)(ws + 150994944);         // 16.78M
  u16* wqkvt = (u16*)(ws + 167772160);       // 6.29M
  u16* wot = (u16*)(ws + 174063616);         // 2.10M
  u16* w1t = (u16*)(ws + 176160768);         // 8.39M
  u16* w2t = (u16*)(ws + 184549376);         // 8.39M  (end ~193M)

  // 1. converts / transposes
  cvt_f32_bf16<<<8192, 256, 0, stream>>>(x, xb, 2097152);
  transpose_cvt<<<dim3(96, 32), 256, 0, stream>>>(Wqkv, wqkvt, 1024, 3072);
  transpose_cvt<<<dim3(32, 32), 256, 0, stream>>>(Wo, wot, 1024, 1024);
  transpose_cvt<<<dim3(128, 32), 256, 0, stream>>>(W1, w1t, 1024, 4096);
  transpose_cvt<<<dim3(32, 128), 256, 0, stream>>>(W2, w2t, 4096, 1024);
  // 2. qkv = x @ Wqkv
  gemm128<0, 0, 1><<<dim3(24, 64), 256, 0, stream>>>(xb, wqkvt, qkvb, nullptr, 8192, 3072, 1024);
  // 3. V pre-transpose, then attention
  vtrans<<<dim3(32, 64), 256, 0, stream>>>(qkvb, vtb);
  attn_kernel<<<dim3(32, 64), 256, 0, stream>>>(qkvb, vtb, attnb);
  // 4. proj = attn @ Wo + bo
  gemm128<1, 0, 0><<<dim3(8, 64), 256, 0, stream>>>(attnb, wot, proj, bo, 8192, 1024, 1024);
  // 5. x1 = LN(x + proj)
  ln_kernel<1><<<8192, 256, 0, stream>>>(x, proj, g1, be1, x1f, x1b);
  // 6. h1 = gelu(x1 @ W1 + b1)
  gemm128<1, 1, 1><<<dim3(32, 64), 256, 0, stream>>>(x1b, w1t, h1b, b1, 8192, 4096, 1024);
  // 7. ff = h1 @ W2 + b2
  gemm128<1, 0, 0><<<dim3(8, 64), 256, 0, stream>>>(h1b, w2t, ff, b2, 8192, 1024, 4096);
  // 8. out = LN(x1 + ff)
  ln_kernel<0><<<8192, 256, 0, stream>>>(x1f, ff, g2, be2, out, nullptr);
}

// Round 3
// 501.645 us; speedup vs baseline: 1.4294x; 1.1166x over previous
//
#include <hip/hip_runtime.h>

typedef unsigned short u16;
typedef __attribute__((ext_vector_type(4))) float f32x4;
typedef __attribute__((ext_vector_type(8))) __bf16 bf16x8;
typedef __attribute__((ext_vector_type(8))) unsigned short u16x8;
typedef __attribute__((ext_vector_type(4))) unsigned short u16x4;

__device__ __forceinline__ u16 f2bf(float f) {
  __bf16 h = (__bf16)f;
  union { __bf16 h; u16 u; } v; v.h = h;
  return v.u;
}

__device__ __forceinline__ void async16(const void* g, void* l) {
  __builtin_amdgcn_global_load_lds(
      (const __attribute__((address_space(1))) unsigned int*)g,
      (__attribute__((address_space(3))) unsigned int*)l, 16, 0, 0);
}

// ---------------- elementwise f32 -> bf16 ----------------
__global__ __launch_bounds__(256) void cvt_f32_bf16(const float* __restrict__ in,
                                                    u16* __restrict__ out, int n4) {
  int i = blockIdx.x * 256 + threadIdx.x;
  if (i >= n4) return;
  f32x4 v = *(const f32x4*)(in + (long)i * 4);
  u16x4 o;
#pragma unroll
  for (int j = 0; j < 4; j++) o[j] = f2bf(v[j]);
  *(u16x4*)(out + (long)i * 4) = o;
}

// ---------------- transpose + convert: W[K][N] f32 -> Wt[N][K] bf16 ----------------
__global__ __launch_bounds__(256) void transpose_cvt(const float* __restrict__ W,
                                                     u16* __restrict__ Wt, int K, int N) {
  __shared__ float tile[32][33];
  int n0 = blockIdx.x * 32, k0 = blockIdx.y * 32;
  int tx = threadIdx.x & 31, ty = threadIdx.x >> 5;
#pragma unroll
  for (int i = 0; i < 32; i += 8)
    tile[ty + i][tx] = W[(long)(k0 + ty + i) * N + n0 + tx];
  __syncthreads();
#pragma unroll
  for (int i = 0; i < 32; i += 8)
    Wt[(long)(n0 + ty + i) * K + k0 + tx] = f2bf(tile[tx][ty + i]);
}

// ---------------- V pre-transpose: qkv V block -> vt[bh][64 d][2048 keys] ----------------
__global__ __launch_bounds__(256) void vtrans(const u16* __restrict__ qkv,
                                              u16* __restrict__ vt) {
  const int bh = blockIdx.y, kt = blockIdx.x * 64;
  const int b = bh >> 4, h = bh & 15;
  const long tok0 = (long)b * 2048;
  const int t = threadIdx.x;
  const int r = t >> 3, c8 = (t & 7) * 8;
  u16x8 v0 = *(const u16x8*)&qkv[(tok0 + kt + r) * 3072 + 2048 + h * 64 + c8];
  u16x8 v1 = *(const u16x8*)&qkv[(tok0 + kt + r + 32) * 3072 + 2048 + h * 64 + c8];
#pragma unroll
  for (int j = 0; j < 8; j++) {
    vt[((long)bh * 64 + c8 + j) * 2048 + kt + r] = v0[j];
    vt[((long)bh * 64 + c8 + j) * 2048 + kt + r + 32] = v1[j];
  }
}

// ---------------- GEMM: C[M,N] = A[M,K](bf16) @ Bt[N,K](bf16)^T ----------------
// QSCALE: multiply cols<1024 by 0.125*log2(e) (folds attention scale+exp2 into Q)
template <int BIAS, int GELU, int OBF, int QSCALE>
__global__ __launch_bounds__(256, 2) void gemm128(const u16* __restrict__ A,
                                                  const u16* __restrict__ Bt,
                                                  void* __restrict__ Cp,
                                                  const float* __restrict__ bias,
                                                  int M, int N, int K) {
  __shared__ u16 As[128 * 32];
  __shared__ u16 Bs[128 * 32];
  const int t = threadIdx.x, ln = t & 63, wv = t >> 6;
  const int wr = wv >> 1, wc = wv & 1;
  const int lr = ln & 15, lg = ln >> 4;
  const int m0 = blockIdx.y * 128, n0 = blockIdx.x * 128;

  const u16* gA = A + (long)(m0 + (t >> 2)) * K + (t & 3) * 8;
  const u16* gA2 = gA + (long)64 * K;
  const u16* gB = Bt + (long)(n0 + (t >> 2)) * K + (t & 3) * 8;
  const u16* gB2 = gB + (long)64 * K;
  char* ldsA = (char*)As + wv * 1024;
  char* ldsB = (char*)Bs + wv * 1024;

  f32x4 acc[4][4] = {};

  for (int kt = 0; kt < K; kt += 32) {
    __syncthreads();
    async16(gA, ldsA);
    async16(gA2, ldsA + 4096);
    async16(gB, ldsB);
    async16(gB2, ldsB + 4096);
    gA += 32; gA2 += 32; gB += 32; gB2 += 32;
    __syncthreads();
    bf16x8 aF[4], bF[4];
#pragma unroll
    for (int i = 0; i < 4; i++) {
      aF[i] = *(const bf16x8*)&As[(wr * 64 + i * 16 + lr) * 32 + lg * 8];
      bF[i] = *(const bf16x8*)&Bs[(wc * 64 + i * 16 + lr) * 32 + lg * 8];
    }
#pragma unroll
    for (int i = 0; i < 4; i++)
#pragma unroll
      for (int j = 0; j < 4; j++)
        acc[i][j] = __builtin_amdgcn_mfma_f32_16x16x32_bf16(aF[i], bF[j], acc[i][j], 0, 0, 0);
  }

#pragma unroll
  for (int i = 0; i < 4; i++) {
    int rbase = m0 + wr * 64 + i * 16 + lg * 4;
#pragma unroll
    for (int j = 0; j < 4; j++) {
      int col = n0 + wc * 64 + j * 16 + lr;
      float bv = BIAS ? bias[col] : 0.f;
#pragma unroll
      for (int r = 0; r < 4; r++) {
        float v = acc[i][j][r] + bv;
        if (GELU) v = v / (1.f + __expf(-1.702f * v));
        if (QSCALE && col < 1024) v *= 0.18033688011112043f;
        if (OBF) ((u16*)Cp)[(long)(rbase + r) * N + col] = f2bf(v);
        else ((float*)Cp)[(long)(rbase + r) * N + col] = v;
      }
    }
  }
}

// ---------------- flash attention (swapped QK^T, lane-local softmax) -----
// qkv: [8192][3072] bf16 (Q pre-scaled by 0.125*log2e). vt: [64 bh][64 d][2048 keys].
__global__ __launch_bounds__(256, 4) void attn_kernel(const u16* __restrict__ qkv,
                                                      const u16* __restrict__ vt,
                                                      u16* __restrict__ out) {
  const int b = blockIdx.y >> 4, h = blockIdx.y & 15;
  const int q0 = blockIdx.x * 64;
  const int t = threadIdx.x, wv = t >> 6, ln = t & 63;
  const int lr = ln & 15, lg = ln >> 4;
  __shared__ u16 Ks[2][64 * 64];
  __shared__ u16 Vs[2][64 * 64];
  __shared__ u16 Pl[4][16 * 64];
  const long tok0 = (long)b * 2048;

  // Q fragments (B-operand: col=q=lr, k-elems=head dim)
  bf16x8 aQ[2];
  {
    long row = tok0 + q0 + wv * 16 + lr;
#pragma unroll
    for (int kf = 0; kf < 2; kf++)
      aQ[kf] = *(const bf16x8*)&qkv[row * 3072 + h * 64 + kf * 32 + lg * 8];
  }

  // staging addresses (pre-swizzled global source -> linear LDS dest)
  const int sr = t >> 3;                       // row 0..31 (and +32)
  const int sc = ((t & 7) ^ (sr & 7)) * 8;     // swizzled u16 chunk
  const u16* gK = qkv + (tok0 + sr) * 3072 + 1024 + h * 64 + sc;
  const u16* gV = vt + ((long)(b * 16 + h) * 64 + sr) * 2048 + sc;
  char* dK = (char*)&Ks[0][0] + wv * 1024;
  char* dV = (char*)&Vs[0][0] + wv * 1024;

  float m_i = -1e30f, l_i = 0.f;   // per-lane: state for q = lr (replicated over lg)
  f32x4 accO[4] = {};

  // prologue: stage tile 0 into buffer 0
  async16(gK, dK);
  async16(gK + (long)32 * 3072, dK + 4096);
  async16(gV, dV);
  async16(gV + (long)32 * 2048, dV + 4096);
  gK += (long)64 * 3072; gV += 64;

  for (int it = 0; it < 32; ++it) {
    const int cur = it & 1;
    if (it < 31) {
      char* nK = dK + (cur ^ 1) * 8192;
      char* nV = dV + (cur ^ 1) * 8192;
      async16(gK, nK);
      async16(gK + (long)32 * 3072, nK + 4096);
      async16(gV, nV);
      async16(gV + (long)32 * 2048, nV + 4096);
      gK += (long)64 * 3072; gV += 64;
      asm volatile("s_waitcnt vmcnt(4)" ::: "memory");
    } else {
      asm volatile("s_waitcnt vmcnt(0)" ::: "memory");
    }
    __builtin_amdgcn_s_barrier();
    __builtin_amdgcn_sched_barrier(0);
    const u16* Kc = &Ks[cur][0];
    const u16* Vc = &Vs[cur][0];

    // ---- S^T = K Q^T : lane holds S[k = nc*16+lg*4+r][q = lr] ----
    f32x4 accS[4];
#pragma unroll
    for (int nc = 0; nc < 4; nc++) {
      f32x4 s = {};
#pragma unroll
      for (int kf = 0; kf < 2; kf++) {
        int krow = nc * 16 + lr;
        bf16x8 aK = *(const bf16x8*)&Kc[krow * 64 + ((kf * 32 + lg * 8) ^ ((krow & 7) << 3))];
        s = __builtin_amdgcn_mfma_f32_16x16x32_bf16(aK, aQ[kf], s, 0, 0, 0);
      }
      accS[nc] = s;  // already in log2 domain (Q pre-scaled)
    }

    // ---- lane-local online softmax for q = lr ----
    float tm = accS[0][0];
#pragma unroll
    for (int nc = 0; nc < 4; nc++)
#pragma unroll
      for (int r = 0; r < 4; r++) tm = fmaxf(tm, accS[nc][r]);
    tm = fmaxf(tm, __shfl_xor(tm, 16));
    tm = fmaxf(tm, __shfl_xor(tm, 32));
    float mn = fmaxf(m_i, tm);
    float corr = exp2f(m_i - mn);
    m_i = mn;

    float rs = 0.f;
    u16x4 pw[4];
#pragma unroll
    for (int nc = 0; nc < 4; nc++) {
#pragma unroll
      for (int r = 0; r < 4; r++) {
        float p = exp2f(accS[nc][r] - mn);
        rs += p;
        pw[nc][r] = f2bf(p);
      }
    }
#pragma unroll
    for (int nc = 0; nc < 4; nc++)
      *(u16x4*)&Pl[wv][lr * 64 + ((nc * 16 + lg * 4) ^ ((lr & 7) << 3))] = pw[nc];
    rs += __shfl_xor(rs, 16);
    rs += __shfl_xor(rs, 32);
    l_i = l_i * corr + rs;

    // broadcast corr to PV accumulator rows (q = lg*4+j lives at lane lg*4+j)
    float cb[4];
#pragma unroll
    for (int j = 0; j < 4; j++) cb[j] = __shfl(corr, lg * 4 + j);
#pragma unroll
    for (int d = 0; d < 4; d++)
#pragma unroll
      for (int j = 0; j < 4; j++) accO[d][j] *= cb[j];

    // ---- O += P V (A=P rows q, B=V^T cols d) ----
#pragma unroll
    for (int kf = 0; kf < 2; kf++) {
      bf16x8 aP = *(const bf16x8*)&Pl[wv][lr * 64 + ((kf * 32 + lg * 8) ^ ((lr & 7) << 3))];
#pragma unroll
      for (int d = 0; d < 4; d++) {
        int vrow = d * 16 + lr;
        bf16x8 bV = *(const bf16x8*)&Vc[vrow * 64 + ((kf * 32 + lg * 8) ^ ((vrow & 7) << 3))];
        accO[d] = __builtin_amdgcn_mfma_f32_16x16x32_bf16(aP, bV, accO[d], 0, 0, 0);
      }
    }
    __builtin_amdgcn_s_barrier();
    __builtin_amdgcn_sched_barrier(0);
  }

  float linv = 1.f / l_i;
  float lb[4];
#pragma unroll
  for (int j = 0; j < 4; j++) lb[j] = __shfl(linv, lg * 4 + j);
#pragma unroll
  for (int d = 0; d < 4; d++) {
#pragma unroll
    for (int j = 0; j < 4; j++) {
      float v = accO[d][j] * lb[j];
      out[(tok0 + q0 + wv * 16 + lg * 4 + j) * 1024 + h * 64 + d * 16 + lr] = f2bf(v);
    }
  }
}

// ---------------- fused add + layernorm (1024 cols, 1 row per block) ----------------
template <int WB>
__global__ __launch_bounds__(256) void ln_kernel(const float* __restrict__ xin,
                                                 const float* __restrict__ res,
                                                 const float* __restrict__ g,
                                                 const float* __restrict__ be,
                                                 float* __restrict__ of,
                                                 u16* __restrict__ ob) {
  int row = blockIdx.x, t = threadIdx.x;
  long base = (long)row * 1024 + t * 4;
  f32x4 a = *(const f32x4*)(xin + base);
  f32x4 bv = *(const f32x4*)(res + base);
  f32x4 v = a + bv;
  float s = v[0] + v[1] + v[2] + v[3];
  float ss = v[0] * v[0] + v[1] * v[1] + v[2] * v[2] + v[3] * v[3];
#pragma unroll
  for (int o = 1; o < 64; o <<= 1) { s += __shfl_xor(s, o); ss += __shfl_xor(ss, o); }
  __shared__ float sm[8];
  if ((t & 63) == 0) { sm[t >> 6] = s; sm[4 + (t >> 6)] = ss; }
  __syncthreads();
  s = sm[0] + sm[1] + sm[2] + sm[3];
  ss = sm[4] + sm[5] + sm[6] + sm[7];
  float mu = s * 0.0009765625f;
  float var = ss * 0.0009765625f - mu * mu;
  float inv = rsqrtf(var + 1e-5f);
  f32x4 gg = *(const f32x4*)(g + t * 4);
  f32x4 bb = *(const f32x4*)(be + t * 4);
  f32x4 y;
#pragma unroll
  for (int j = 0; j < 4; j++) y[j] = (v[j] - mu) * inv * gg[j] + bb[j];
  *(f32x4*)(of + base) = y;
  if (WB) {
    u16x4 o4;
#pragma unroll
    for (int j = 0; j < 4; j++) o4[j] = f2bf(y[j]);
    *(u16x4*)(ob + base) = o4;
  }
}

// ---------------- launch ----------------
extern "C" void kernel_launch(void* const* d_in, const int* in_sizes, int n_in,
                              void* d_out, int out_size, void* d_ws, size_t ws_size,
                              hipStream_t stream) {
  const float* x = (const float*)d_in[0];
  const float* Wqkv = (const float*)d_in[1];
  const float* Wo = (const float*)d_in[2];
  const float* bo = (const float*)d_in[3];
  const float* g1 = (const float*)d_in[4];
  const float* be1 = (const float*)d_in[5];
  const float* W1 = (const float*)d_in[6];
  const float* b1 = (const float*)d_in[7];
  const float* W2 = (const float*)d_in[8];
  const float* b2 = (const float*)d_in[9];
  const float* g2 = (const float*)d_in[10];
  const float* be2 = (const float*)d_in[11];
  float* out = (float*)d_out;
  char* ws = (char*)d_ws;

  // workspace layout (bytes); regions overlaid by lifetime
  u16* xb = (u16*)(ws + 0);                  // 16.78M  [dead after GEMM1]
  u16* qkvb = (u16*)(ws + 16777216);         // 50.33M  [dead after attn]
  u16* h1b = (u16*)(ws + 0);                 // 67.11M  reuses xb+qkvb
  u16* attnb = (u16*)(ws + 67108864);        // 16.78M  [dead after GEMM2]
  u16* vtb = (u16*)(ws + 83886080);          // 16.78M  [dead after attn]
  float* proj = (float*)(ws + 83886080);     // 33.55M  reuses vtb (written after attn)
  float* ff = (float*)(ws + 67108864);       // 33.55M  reuses attnb(+proj head)
  float* x1f = (float*)(ws + 117440512);     // 33.55M
  u16* x1b = (u16*)(ws + 150994944);         // 16.78M
  u16* wqkvt = (u16*)(ws + 167772160);       // 6.29M
  u16* wot = (u16*)(ws + 174063616);         // 2.10M
  u16* w1t = (u16*)(ws + 176160768);         // 8.39M
  u16* w2t = (u16*)(ws + 184549376);         // 8.39M  (end ~193M)

  // 1. converts / transposes
  cvt_f32_bf16<<<8192, 256, 0, stream>>>(x, xb, 2097152);
  transpose_cvt<<<dim3(96, 32), 256, 0, stream>>>(Wqkv, wqkvt, 1024, 3072);
  transpose_cvt<<<dim3(32, 32), 256, 0, stream>>>(Wo, wot, 1024, 1024);
  transpose_cvt<<<dim3(128, 32), 256, 0, stream>>>(W1, w1t, 1024, 4096);
  transpose_cvt<<<dim3(32, 128), 256, 0, stream>>>(W2, w2t, 4096, 1024);
  // 2. qkv = x @ Wqkv  (Q cols pre-scaled for exp2-domain softmax)
  gemm128<0, 0, 1, 1><<<dim3(24, 64), 256, 0, stream>>>(xb, wqkvt, qkvb, nullptr, 8192, 3072, 1024);
  // 3. V pre-transpose, then attention
  vtrans<<<dim3(32, 64), 256, 0, stream>>>(qkvb, vtb);
  attn_kernel<<<dim3(32, 64), 256, 0, stream>>>(qkvb, vtb, attnb);
  // 4. proj = attn @ Wo + bo
  gemm128<1, 0, 0, 0><<<dim3(8, 64), 256, 0, stream>>>(attnb, wot, proj, bo, 8192, 1024, 1024);
  // 5. x1 = LN(x + proj)
  ln_kernel<1><<<8192, 256, 0, stream>>>(x, proj, g1, be1, x1f, x1b);
  // 6. h1 = gelu(x1 @ W1 + b1)
  gemm128<1, 1, 1, 0><<<dim3(32, 64), 256, 0, stream>>>(x1b, w1t, h1b, b1, 8192, 4096, 1024);
  // 7. ff = h1 @ W2 + b2
  gemm128<1, 0, 0, 0><<<dim3(8, 64), 256, 0, stream>>>(h1b, w2t, ff, b2, 8192, 1024, 4096);
  // 8. out = LN(x1 + ff)
  ln_kernel<0><<<8192, 256, 0, stream>>>(x1f, ff, g2, be2, out, nullptr);
}